// Round 3
// baseline (37041.025 us; speedup 1.0000x reference)
//
#include <hip/hip_runtime.h>
#include <hip/hip_bf16.h>
#include <stdint.h>

typedef unsigned short ushort_t;

#define H   512
#define E   128
#define NC  27
#define NE  28
#define B   256
#define T   512
#define FH  2048        // 4*H
#define NPH (T + 2)     // phases 0..T+1
#define NBLK 224        // 64 L0 + 128 L1 + 32 OUT
#define LDS_BYTES (96 * 1024)

typedef __bf16 bf16x8 __attribute__((ext_vector_type(8)));
typedef float  f32x4  __attribute__((ext_vector_type(4)));

__device__ __forceinline__ ushort_t f2b(float x) {
    uint32_t u = __float_as_uint(x);
    uint32_t r = (u + 0x7FFFu + ((u >> 16) & 1u)) >> 16;
    return (ushort_t)r;
}
__device__ __forceinline__ float sigm(float x) {
    return 1.f / (1.f + __expf(-x));
}
__device__ __forceinline__ bf16x8 ldg8(const ushort_t* p) {
    return *(const bf16x8*)p;
}

// ---------------- setup kernels ----------------

__global__ void k_init(int* __restrict__ cnt) {
    int i = blockIdx.x * blockDim.x + threadIdx.x;
    if (i < NPH) cnt[i] = 0;
}

__global__ void k_g0(const float* __restrict__ embed, const float* __restrict__ Wih0,
                     const float* __restrict__ bih, const float* __restrict__ bhh,
                     float* __restrict__ G0, float* __restrict__ bias1) {
    int i = blockIdx.x * blockDim.x + threadIdx.x;
    if (i < 2 * NE * FH) {
        int d = i / (NE * FH);
        int rem = i % (NE * FH);
        int e = rem / FH;
        int n = rem % FH;
        const float* er = embed + (size_t)e * E;
        const float* wr = Wih0 + ((size_t)d * FH + n) * E;
        float s = 0.f;
        #pragma unroll 8
        for (int k = 0; k < E; ++k) s += er[k] * wr[k];
        G0[i] = s + bih[(size_t)d * FH + n] + bhh[(size_t)d * FH + n];
    }
    if (i < 2 * FH) bias1[i] = bih[2 * FH + i] + bhh[2 * FH + i];
}

__global__ void k_state(const float* __restrict__ h0, const float* __restrict__ c0,
                        float* __restrict__ cst, ushort_t* __restrict__ hb16) {
    int i = blockIdx.x * blockDim.x + threadIdx.x;
    if (i >= 4 * B * H) return;
    cst[i] = c0[i];
    int cell = i / (B * H);
    int rem  = i % (B * H);
    hb16[((size_t)(cell * 2 + 1)) * (B * H) + rem] = f2b(h0[i]);   // parity 1 = step -1
}

__global__ void k_len(const int* __restrict__ lens, float* __restrict__ out_len) {
    int i = threadIdx.x;
    if (i < B) out_len[i] = (float)lens[i];
}

// ---------------- persistent kernel ----------------
__device__ __forceinline__ void gbar(int* cnt, int p) {
    __syncthreads();
    if (threadIdx.x == 0) {
        __threadfence();
        __hip_atomic_fetch_add(&cnt[p], 1, __ATOMIC_RELEASE, __HIP_MEMORY_SCOPE_AGENT);
        while (__hip_atomic_load(&cnt[p], __ATOMIC_ACQUIRE, __HIP_MEMORY_SCOPE_AGENT) < NBLK) {
            __builtin_amdgcn_s_sleep(1);
        }
    }
    __syncthreads();
}

// Phase p: L0 step t=p (p<T); L1 step s=p-1 (1<=p<=T); OUT logits t2=p-2 (p>=2).
// hb16: [cell][parity][B][H] bf16, parity(step)=step&1.
__global__ __launch_bounds__(512, 2) void k_persist(
    const float* __restrict__ Whh, const float* __restrict__ Wih1,
    const float* __restrict__ G0, const float* __restrict__ bias1,
    float* __restrict__ cst, ushort_t* __restrict__ hb16,
    const int* __restrict__ tok, const int* __restrict__ lens,
    const float* __restrict__ Wout, const float* __restrict__ bout,
    float* __restrict__ out, int* __restrict__ cnt)
{
    extern __shared__ char smem[];
    const int bid = blockIdx.x;
    const int tid = threadIdx.x;
    const int lane = tid & 63, wave = tid >> 6;
    const int lrow = lane & 15, kg = lane >> 4;
    const int row0 = wave * 32;
    const int BH = B * H;
    const int sw16 = (lrow & 7) << 4;

    // ---- one-time: stage weights into LDS (f32 -> bf16, XOR-swizzled) ----
    if (bid < 64) {
        const int cell = bid >> 5, jt = bid & 31, j0 = jt * 16;
        const float* Wsrc = Whh + (size_t)cell * FH * H;
        for (int r = wave; r < 64; r += 8) {
            int grow = (r >> 4) * 512 + j0 + (r & 15);
            const float* src = Wsrc + (size_t)grow * H;
            int sw = (r & 7) << 4;
            for (int c = lane; c < H; c += 64) {
                int byte = ((r * H + c) * 2) ^ sw;
                *(ushort_t*)(smem + byte) = f2b(src[c]);
            }
        }
    } else if (bid < 192) {
        const int q = bid - 64, cell = 2 + (q >> 6), jt = q & 63, j0 = jt * 8;
        const float* Wi = Wih1 + (size_t)(cell - 2) * FH * (2 * H);
        const float* Wh = Whh + (size_t)cell * FH * H;
        for (int r = wave; r < 32; r += 8) {
            int grow = (r >> 3) * 512 + j0 + (r & 7);
            const float* si = Wi + (size_t)grow * (2 * H);
            const float* sh = Wh + (size_t)grow * H;
            int sw = (r & 7) << 4;
            for (int c = lane; c < 1536; c += 64) {
                float v = (c < 1024) ? si[c] : sh[c - 1024];
                int byte = ((r * 1536 + c) * 2) ^ sw;
                *(ushort_t*)(smem + byte) = f2b(v);
            }
        }
    } else {
        for (int r = wave; r < NC; r += 8) {
            const float* src = Wout + (size_t)r * (2 * H);
            int sw = (r & 7) << 4;
            for (int c = lane; c < 2 * H; c += 64) {
                int byte = ((r * (2 * H) + c) * 2) ^ sw;
                *(ushort_t*)(smem + byte) = f2b(src[c]);
            }
        }
    }
    __syncthreads();

    if (bid < 64) {
        // ================= layer 0 =================
        const int cell = bid >> 5, jt = bid & 31, j0 = jt * 16;
        const int j = j0 + lrow;
        const size_t ro = (size_t)(row0 + lrow) * H + kg * 8;

        for (int p = 0; p < NPH; ++p) {
            if (p < T) {
                const int parR = (p + 1) & 1, parW = p & 1;
                const ushort_t* ar0 = hb16 + (size_t)(cell * 2 + parR) * BH + ro;
                const ushort_t* ar1 = ar0 + (size_t)16 * H;

                bf16x8 rb0[8], rb1[8];
                #pragma unroll
                for (int q = 0; q < 8; ++q) {
                    rb0[q] = ldg8(ar0 + q * 32);
                    rb1[q] = ldg8(ar1 + q * 32);
                }

                // epilogue prefetch (overlaps ring prime latency)
                int tkv[8]; float cv[8];
                #pragma unroll
                for (int i = 0; i < 8; ++i) {
                    int bb = row0 + (i >> 2) * 16 + kg * 4 + (i & 3);
                    tkv[i] = tok[(size_t)bb * T + p];
                    cv[i]  = cst[((size_t)cell * B + bb) * H + j];
                }
                float g0v[8][4];
                #pragma unroll
                for (int i = 0; i < 8; ++i) {
                    const float* g0 = G0 + ((size_t)cell * NE + tkv[i]) * FH + j;
                    #pragma unroll
                    for (int g = 0; g < 4; ++g) g0v[i][g] = g0[g * 512];
                }

                f32x4 acc[2][4];
                #pragma unroll
                for (int m = 0; m < 2; ++m)
                    #pragma unroll
                    for (int g = 0; g < 4; ++g) acc[m][g] = (f32x4){0.f, 0.f, 0.f, 0.f};

                #pragma unroll
                for (int t = 0; t < 16; ++t) {
                    bf16x8 a0 = rb0[t & 7];
                    bf16x8 a1 = rb1[t & 7];
                    if (t + 8 < 16) {
                        rb0[t & 7] = ldg8(ar0 + (t + 8) * 32);
                        rb1[t & 7] = ldg8(ar1 + (t + 8) * 32);
                    }
                    int cb = (kg * 16 + t * 64) ^ sw16;
                    #pragma unroll
                    for (int g = 0; g < 4; ++g) {
                        bf16x8 bb = *(const bf16x8*)(smem + (g * 16 + lrow) * 1024 + cb);
                        acc[0][g] = __builtin_amdgcn_mfma_f32_16x16x32_bf16(a0, bb, acc[0][g], 0, 0, 0);
                        acc[1][g] = __builtin_amdgcn_mfma_f32_16x16x32_bf16(a1, bb, acc[1][g], 0, 0, 0);
                    }
                }

                #pragma unroll
                for (int i = 0; i < 8; ++i) {
                    int mf = i >> 2, r = i & 3;
                    int bb = row0 + mf * 16 + kg * 4 + r;
                    float gi = acc[mf][0][r] + g0v[i][0];
                    float gf = acc[mf][1][r] + g0v[i][1];
                    float gg = acc[mf][2][r] + g0v[i][2];
                    float go = acc[mf][3][r] + g0v[i][3];
                    float ii = sigm(gi), ff = sigm(gf), oo = sigm(go);
                    float tg = tanhf(gg);
                    size_t ci = ((size_t)cell * B + bb) * H + j;
                    float cn = ff * cv[i] + ii * tg;
                    cst[ci] = cn;
                    float hn = oo * tanhf(cn);
                    hb16[((size_t)(cell * 2 + parW) * B + bb) * H + j] = f2b(hn);
                }
            }
            if (p < NPH - 1) gbar(cnt, p);
        }
    } else if (bid < 192) {
        // ================= layer 1 =================
        const int q = bid - 64, cell = 2 + (q >> 6), jt = q & 63, j0 = jt * 8;
        const int cc = lrow;
        const int jj = j0 + (cc & 7);
        const int mfS = cc >> 3;
        const size_t ro = (size_t)(row0 + lrow) * H + kg * 8;

        float b1v[4];
        #pragma unroll
        for (int g = 0; g < 4; ++g) b1v[g] = bias1[(size_t)(cell - 2) * FH + g * 512 + jj];

        for (int p = 0; p < NPH; ++p) {
            if (p >= 1 && p <= T) {
                const int parY  = (p + 1) & 1;
                const int parR2 = p & 1;
                const int parW  = (p + 1) & 1;
                const ushort_t* base0 = hb16 + (size_t)(0 * 2 + parY) * BH + ro;
                const ushort_t* base1 = hb16 + (size_t)(1 * 2 + parY) * BH + ro;
                const ushort_t* base2 = hb16 + (size_t)(cell * 2 + parR2) * BH + ro;

                bf16x8 rb0[8], rb1[8];
                #pragma unroll
                for (int qq = 0; qq < 8; ++qq) {
                    rb0[qq] = ldg8(base0 + qq * 32);
                    rb1[qq] = ldg8(base0 + (size_t)16 * H + qq * 32);
                }

                float cv[4];
                #pragma unroll
                for (int r = 0; r < 4; ++r) {
                    int bb = row0 + mfS * 16 + kg * 4 + r;
                    cv[r] = cst[((size_t)cell * B + bb) * H + jj];
                }

                f32x4 acc[2][2];
                #pragma unroll
                for (int m = 0; m < 2; ++m)
                    #pragma unroll
                    for (int n = 0; n < 2; ++n) acc[m][n] = (f32x4){0.f, 0.f, 0.f, 0.f};

                #pragma unroll
                for (int t = 0; t < 48; ++t) {
                    bf16x8 a0 = rb0[t & 7];
                    bf16x8 a1 = rb1[t & 7];
                    int tn = t + 8;
                    if (tn < 48) {
                        const ushort_t* bp = (tn < 16) ? base0 : (tn < 32) ? base1 : base2;
                        int off = (tn & 15) * 32;
                        rb0[t & 7] = ldg8(bp + off);
                        rb1[t & 7] = ldg8(bp + (size_t)16 * H + off);
                    }
                    int cb = (t * 64 + kg * 16) ^ sw16;
                    bf16x8 b0 = *(const bf16x8*)(smem + lrow * 3072 + cb);
                    bf16x8 b1 = *(const bf16x8*)(smem + (16 + lrow) * 3072 + cb);
                    acc[0][0] = __builtin_amdgcn_mfma_f32_16x16x32_bf16(a0, b0, acc[0][0], 0, 0, 0);
                    acc[0][1] = __builtin_amdgcn_mfma_f32_16x16x32_bf16(a0, b1, acc[0][1], 0, 0, 0);
                    acc[1][0] = __builtin_amdgcn_mfma_f32_16x16x32_bf16(a1, b0, acc[1][0], 0, 0, 0);
                    acc[1][1] = __builtin_amdgcn_mfma_f32_16x16x32_bf16(a1, b1, acc[1][1], 0, 0, 0);
                }

                #pragma unroll
                for (int r = 0; r < 4; ++r) {
                    float a00 = acc[0][0][r], a01 = acc[0][1][r];
                    float a10 = acc[1][0][r], a11 = acc[1][1][r];
                    float e00 = __shfl_xor(a00, 8);
                    float e01 = __shfl_xor(a01, 8);
                    float e10 = __shfl_xor(a10, 8);
                    float e11 = __shfl_xor(a11, 8);
                    float gi, gf, gg, go;
                    if (mfS == 0) { gi = a00; gf = e00; gg = a01; go = e01; }
                    else          { gi = e10; gf = a10; gg = e11; go = a11; }
                    gi += b1v[0]; gf += b1v[1]; gg += b1v[2]; go += b1v[3];
                    int bb = row0 + mfS * 16 + kg * 4 + r;
                    float ii = sigm(gi), ff = sigm(gf), oo = sigm(go);
                    float tg = tanhf(gg);
                    size_t ci = ((size_t)cell * B + bb) * H + jj;
                    float cn = ff * cv[r] + ii * tg;
                    cst[ci] = cn;
                    float hn = oo * tanhf(cn);
                    hb16[((size_t)(cell * 2 + parW) * B + bb) * H + jj] = f2b(hn);
                }
            }
            if (p < NPH - 1) gbar(cnt, p);
        }
    } else {
        // ================= logits =================
        const int b = (bid - 192) * 8 + wave;
        const int c = lane & 31, kh = lane >> 5;
        const int sww = (c & 7) << 4;
        const int rowbase = c * 2048;
        const int lenb = lens[b];
        const float bo = (c < NC) ? bout[c] : 0.f;

        for (int p = 0; p < NPH; ++p) {
            if (p >= 2) {
                const int t2 = p - 2, parL = p & 1;
                const ushort_t* y2 = hb16 + (size_t)((2 + kh) * 2 + parL) * BH + (size_t)b * H;
                float sum = 0.f;
                if (c < NC) {
                    bf16x8 rb[8];
                    #pragma unroll
                    for (int qq = 0; qq < 8; ++qq) rb[qq] = ldg8(y2 + qq * 8);
                    #pragma unroll
                    for (int t = 0; t < 64; ++t) {
                        bf16x8 v = rb[t & 7];
                        if (t + 8 < 64) rb[t & 7] = ldg8(y2 + (t + 8) * 8);
                        int cb = ((kh * 1024 + t * 16)) ^ sww;
                        bf16x8 w = *(const bf16x8*)(smem + rowbase + cb);
                        #pragma unroll
                        for (int i = 0; i < 8; ++i) sum += (float)v[i] * (float)w[i];
                    }
                }
                sum += __shfl_xor(sum, 32);
                if (kh == 0 && c < NC) {
                    float val = sum + bo;
                    out[((size_t)b * T + t2) * NC + c] = (t2 < lenb) ? val : 0.f;
                }
            }
            if (p < NPH - 1) gbar(cnt, p);
        }
    }
}

// ---------------- launch ----------------

extern "C" void kernel_launch(void* const* d_in, const int* in_sizes, int n_in,
                              void* d_out, int out_size, void* d_ws, size_t ws_size,
                              hipStream_t stream) {
    const int*   tok   = (const int*)d_in[0];
    const int*   lens  = (const int*)d_in[1];
    const float* h0    = (const float*)d_in[2];
    const float* c0    = (const float*)d_in[3];
    const float* embed = (const float*)d_in[4];
    const float* Wih0  = (const float*)d_in[5];
    const float* Wih1  = (const float*)d_in[6];
    const float* Whh   = (const float*)d_in[7];
    const float* bih   = (const float*)d_in[8];
    const float* bhh   = (const float*)d_in[9];
    const float* Wout  = (const float*)d_in[10];
    const float* bout  = (const float*)d_in[11];
    float* out = (float*)d_out;

    ushort_t* hb16  = (ushort_t*)d_ws;                      // [4][2][B][H] bf16
    float*    fbase = (float*)(hb16 + (size_t)4 * 2 * B * H);
    float*    cst   = fbase;                                // [4][B][H] f32
    float*    G0    = cst + (size_t)4 * B * H;              // [2][28][2048] f32
    float*    bias1 = G0 + 2 * NE * FH;                     // [2][2048] f32
    int*      cnt   = (int*)(bias1 + 2 * FH);               // [NPH]

    (void)hipFuncSetAttribute((const void*)k_persist,
                              hipFuncAttributeMaxDynamicSharedMemorySize, LDS_BYTES);

    k_init<<<(NPH + 255) / 256, 256, 0, stream>>>(cnt);
    k_g0<<<(2 * NE * FH + 255) / 256, 256, 0, stream>>>(embed, Wih0, bih, bhh, G0, bias1);
    k_state<<<(4 * B * H + 255) / 256, 256, 0, stream>>>(h0, c0, cst, hb16);
    k_len<<<1, 256, 0, stream>>>(lens, out + (size_t)B * T * NC);

    k_persist<<<NBLK, 512, LDS_BYTES, stream>>>(Whh, Wih1, G0, bias1, cst, hb16,
                                                tok, lens, Wout, bout, out, cnt);
}

// Round 4
// 28657.773 us; speedup vs baseline: 1.2925x; 1.2925x over previous
//
#include <hip/hip_runtime.h>
#include <hip/hip_bf16.h>
#include <stdint.h>

typedef unsigned short ushort_t;
typedef unsigned long long u64_t;

#define H   512
#define E   128
#define NC  27
#define NE  28
#define B   256
#define T   512
#define FH  2048        // 4*H
#define NPH (T + 2)     // phases 0..T+1
#define NBLK 224        // 64 L0 + 128 L1 + 32 OUT
#define NCELL 16
#define LDS_BYTES (96 * 1024)

typedef __bf16 bf16x8 __attribute__((ext_vector_type(8)));
typedef float  f32x4  __attribute__((ext_vector_type(4)));

__device__ __forceinline__ ushort_t f2b(float x) {
    uint32_t u = __float_as_uint(x);
    uint32_t r = (u + 0x7FFFu + ((u >> 16) & 1u)) >> 16;
    return (ushort_t)r;
}
__device__ __forceinline__ float sigm(float x) {
    return 1.f / (1.f + __expf(-x));
}

// LLC-coherent (agent-scope, relaxed) 16B load: 2x u64 atomic loads -> sc0/sc1 bits,
// bypasses (possibly stale) L1/L2 without any cache invalidation.
__device__ __forceinline__ bf16x8 ldc16(const ushort_t* p) {
    union { u64_t q[2]; bf16x8 v; } u;
    u.q[0] = __hip_atomic_load((const u64_t*)p,       __ATOMIC_RELAXED, __HIP_MEMORY_SCOPE_AGENT);
    u.q[1] = __hip_atomic_load(((const u64_t*)p) + 1, __ATOMIC_RELAXED, __HIP_MEMORY_SCOPE_AGENT);
    return u.v;
}
// LLC-coherent 2-byte store (write-through, no L2 dirtying).
__device__ __forceinline__ void stc2(ushort_t* p, ushort_t v) {
    __hip_atomic_store(p, v, __ATOMIC_RELAXED, __HIP_MEMORY_SCOPE_AGENT);
}

// ---------------- setup kernels ----------------

__global__ void k_init(int* __restrict__ cnt) {
    int i = blockIdx.x * blockDim.x + threadIdx.x;
    if (i < NPH * NCELL) cnt[i] = 0;
}

__global__ void k_g0(const float* __restrict__ embed, const float* __restrict__ Wih0,
                     const float* __restrict__ bih, const float* __restrict__ bhh,
                     float* __restrict__ G0, float* __restrict__ bias1) {
    int i = blockIdx.x * blockDim.x + threadIdx.x;
    if (i < 2 * NE * FH) {
        int d = i / (NE * FH);
        int rem = i % (NE * FH);
        int e = rem / FH;
        int n = rem % FH;
        const float* er = embed + (size_t)e * E;
        const float* wr = Wih0 + ((size_t)d * FH + n) * E;
        float s = 0.f;
        #pragma unroll 8
        for (int k = 0; k < E; ++k) s += er[k] * wr[k];
        G0[i] = s + bih[(size_t)d * FH + n] + bhh[(size_t)d * FH + n];
    }
    if (i < 2 * FH) bias1[i] = bih[2 * FH + i] + bhh[2 * FH + i];
}

__global__ void k_state(const float* __restrict__ h0, const float* __restrict__ c0,
                        float* __restrict__ cst, ushort_t* __restrict__ hb16) {
    int i = blockIdx.x * blockDim.x + threadIdx.x;
    if (i >= 4 * B * H) return;
    cst[i] = c0[i];
    int cell = i / (B * H);
    int rem  = i % (B * H);
    hb16[((size_t)(cell * 2 + 1)) * (B * H) + rem] = f2b(h0[i]);   // parity 1 = step -1
}

__global__ void k_len(const int* __restrict__ lens, float* __restrict__ out_len) {
    int i = threadIdx.x;
    if (i < B) out_len[i] = (float)lens[i];
}

// ---------------- grid barrier (fence-free) ----------------
// __syncthreads drains all waves' vmem (incl. the sc-flagged hb16 stores);
// then a relaxed agent add + relaxed all-poll. No wbL2/invL2 anywhere.
__device__ __forceinline__ void gbar(int* cnt, int p) {
    __syncthreads();
    if (threadIdx.x == 0) {
        int* base = cnt + p * NCELL;
        __hip_atomic_fetch_add(base + (blockIdx.x & (NCELL - 1)), 1,
                               __ATOMIC_RELAXED, __HIP_MEMORY_SCOPE_AGENT);
        int total;
        do {
            total = 0;
            #pragma unroll
            for (int c2 = 0; c2 < NCELL; ++c2)
                total += __hip_atomic_load(base + c2, __ATOMIC_RELAXED, __HIP_MEMORY_SCOPE_AGENT);
            if (total < NBLK) __builtin_amdgcn_s_sleep(2);
        } while (total < NBLK);
    }
    __builtin_amdgcn_sched_barrier(0);
    __syncthreads();
}

// Phase p: L0 step t=p (p<T); L1 step s=p-1 (1<=p<=T); OUT logits t2=p-2 (p>=2).
// hb16: [cell][parity][B][H] bf16, parity(step)=step&1.
__global__ __launch_bounds__(512, 2) void k_persist(
    const float* __restrict__ Whh, const float* __restrict__ Wih1,
    const float* __restrict__ G0, const float* __restrict__ bias1,
    float* __restrict__ cst, ushort_t* __restrict__ hb16,
    const int* __restrict__ tok, const int* __restrict__ lens,
    const float* __restrict__ Wout, const float* __restrict__ bout,
    float* __restrict__ out, int* __restrict__ cnt)
{
    extern __shared__ char smem[];
    const int bid = blockIdx.x;
    const int tid = threadIdx.x;
    const int lane = tid & 63, wave = tid >> 6;
    const int lrow = lane & 15, kg = lane >> 4;
    const int row0 = wave * 32;
    const int BH = B * H;
    const int sw16 = (lrow & 7) << 4;

    // ---- one-time: stage weights into LDS (f32 -> bf16, XOR-swizzled) ----
    if (bid < 64) {
        const int cell = bid >> 5, jt = bid & 31, j0 = jt * 16;
        const float* Wsrc = Whh + (size_t)cell * FH * H;
        for (int r = wave; r < 64; r += 8) {
            int grow = (r >> 4) * 512 + j0 + (r & 15);
            const float* src = Wsrc + (size_t)grow * H;
            int sw = (r & 7) << 4;
            for (int c = lane; c < H; c += 64) {
                int byte = ((r * H + c) * 2) ^ sw;
                *(ushort_t*)(smem + byte) = f2b(src[c]);
            }
        }
    } else if (bid < 192) {
        const int q = bid - 64, cell = 2 + (q >> 6), jt = q & 63, j0 = jt * 8;
        const float* Wi = Wih1 + (size_t)(cell - 2) * FH * (2 * H);
        const float* Wh = Whh + (size_t)cell * FH * H;
        for (int r = wave; r < 32; r += 8) {
            int grow = (r >> 3) * 512 + j0 + (r & 7);
            const float* si = Wi + (size_t)grow * (2 * H);
            const float* sh = Wh + (size_t)grow * H;
            int sw = (r & 7) << 4;
            for (int c = lane; c < 1536; c += 64) {
                float v = (c < 1024) ? si[c] : sh[c - 1024];
                int byte = ((r * 1536 + c) * 2) ^ sw;
                *(ushort_t*)(smem + byte) = f2b(v);
            }
        }
    } else {
        for (int r = wave; r < NC; r += 8) {
            const float* src = Wout + (size_t)r * (2 * H);
            int sw = (r & 7) << 4;
            for (int c = lane; c < 2 * H; c += 64) {
                int byte = ((r * (2 * H) + c) * 2) ^ sw;
                *(ushort_t*)(smem + byte) = f2b(src[c]);
            }
        }
    }
    __syncthreads();

    if (bid < 64) {
        // ================= layer 0 =================
        const int cell = bid >> 5, jt = bid & 31, j0 = jt * 16;
        const int j = j0 + lrow;
        const size_t ro = (size_t)(row0 + lrow) * H + kg * 8;

        for (int p = 0; p < NPH; ++p) {
            if (p < T) {
                const int parR = (p + 1) & 1, parW = p & 1;
                const ushort_t* ar0 = hb16 + (size_t)(cell * 2 + parR) * BH + ro;
                const ushort_t* ar1 = ar0 + (size_t)16 * H;

                bf16x8 rb0[8], rb1[8];
                #pragma unroll
                for (int q = 0; q < 8; ++q) {
                    rb0[q] = ldc16(ar0 + q * 32);
                    rb1[q] = ldc16(ar1 + q * 32);
                }

                // epilogue prefetch (L2-cached, cheap now)
                int tkv[8]; float cv[8];
                #pragma unroll
                for (int i = 0; i < 8; ++i) {
                    int bb = row0 + (i >> 2) * 16 + kg * 4 + (i & 3);
                    tkv[i] = tok[(size_t)bb * T + p];
                    cv[i]  = cst[((size_t)cell * B + bb) * H + j];
                }
                float g0v[8][4];
                #pragma unroll
                for (int i = 0; i < 8; ++i) {
                    const float* g0 = G0 + ((size_t)cell * NE + tkv[i]) * FH + j;
                    #pragma unroll
                    for (int g = 0; g < 4; ++g) g0v[i][g] = g0[g * 512];
                }

                f32x4 acc[2][4];
                #pragma unroll
                for (int m = 0; m < 2; ++m)
                    #pragma unroll
                    for (int g = 0; g < 4; ++g) acc[m][g] = (f32x4){0.f, 0.f, 0.f, 0.f};

                #pragma unroll
                for (int t = 0; t < 16; ++t) {
                    bf16x8 a0 = rb0[t & 7];
                    bf16x8 a1 = rb1[t & 7];
                    if (t + 8 < 16) {
                        rb0[t & 7] = ldc16(ar0 + (t + 8) * 32);
                        rb1[t & 7] = ldc16(ar1 + (t + 8) * 32);
                    }
                    int cb = (kg * 16 + t * 64) ^ sw16;
                    #pragma unroll
                    for (int g = 0; g < 4; ++g) {
                        bf16x8 bb = *(const bf16x8*)(smem + (g * 16 + lrow) * 1024 + cb);
                        acc[0][g] = __builtin_amdgcn_mfma_f32_16x16x32_bf16(a0, bb, acc[0][g], 0, 0, 0);
                        acc[1][g] = __builtin_amdgcn_mfma_f32_16x16x32_bf16(a1, bb, acc[1][g], 0, 0, 0);
                    }
                }

                #pragma unroll
                for (int i = 0; i < 8; ++i) {
                    int mf = i >> 2, r = i & 3;
                    int bb = row0 + mf * 16 + kg * 4 + r;
                    float gi = acc[mf][0][r] + g0v[i][0];
                    float gf = acc[mf][1][r] + g0v[i][1];
                    float gg = acc[mf][2][r] + g0v[i][2];
                    float go = acc[mf][3][r] + g0v[i][3];
                    float ii = sigm(gi), ff = sigm(gf), oo = sigm(go);
                    float tg = tanhf(gg);
                    size_t ci = ((size_t)cell * B + bb) * H + j;
                    float cn = ff * cv[i] + ii * tg;
                    cst[ci] = cn;
                    float hn = oo * tanhf(cn);
                    stc2(&hb16[((size_t)(cell * 2 + parW) * B + bb) * H + j], f2b(hn));
                }
            }
            if (p < NPH - 1) gbar(cnt, p);
        }
    } else if (bid < 192) {
        // ================= layer 1 =================
        const int q = bid - 64, cell = 2 + (q >> 6), jt = q & 63, j0 = jt * 8;
        const int cc = lrow;
        const int jj = j0 + (cc & 7);
        const int mfS = cc >> 3;
        const size_t ro = (size_t)(row0 + lrow) * H + kg * 8;

        float b1v[4];
        #pragma unroll
        for (int g = 0; g < 4; ++g) b1v[g] = bias1[(size_t)(cell - 2) * FH + g * 512 + jj];

        for (int p = 0; p < NPH; ++p) {
            if (p >= 1 && p <= T) {
                const int parY  = (p + 1) & 1;
                const int parR2 = p & 1;
                const int parW  = (p + 1) & 1;
                const ushort_t* base0 = hb16 + (size_t)(0 * 2 + parY) * BH + ro;
                const ushort_t* base1 = hb16 + (size_t)(1 * 2 + parY) * BH + ro;
                const ushort_t* base2 = hb16 + (size_t)(cell * 2 + parR2) * BH + ro;

                bf16x8 rb0[8], rb1[8];
                #pragma unroll
                for (int qq = 0; qq < 8; ++qq) {
                    rb0[qq] = ldc16(base0 + qq * 32);
                    rb1[qq] = ldc16(base0 + (size_t)16 * H + qq * 32);
                }

                float cv[4];
                #pragma unroll
                for (int r = 0; r < 4; ++r) {
                    int bb = row0 + mfS * 16 + kg * 4 + r;
                    cv[r] = cst[((size_t)cell * B + bb) * H + jj];
                }

                f32x4 acc[2][2];
                #pragma unroll
                for (int m = 0; m < 2; ++m)
                    #pragma unroll
                    for (int n = 0; n < 2; ++n) acc[m][n] = (f32x4){0.f, 0.f, 0.f, 0.f};

                #pragma unroll
                for (int t = 0; t < 48; ++t) {
                    bf16x8 a0 = rb0[t & 7];
                    bf16x8 a1 = rb1[t & 7];
                    int tn = t + 8;
                    if (tn < 48) {
                        const ushort_t* bp = (tn < 16) ? base0 : (tn < 32) ? base1 : base2;
                        int off = (tn & 15) * 32;
                        rb0[t & 7] = ldc16(bp + off);
                        rb1[t & 7] = ldc16(bp + (size_t)16 * H + off);
                    }
                    int cb = (t * 64 + kg * 16) ^ sw16;
                    bf16x8 b0 = *(const bf16x8*)(smem + lrow * 3072 + cb);
                    bf16x8 b1 = *(const bf16x8*)(smem + (16 + lrow) * 3072 + cb);
                    acc[0][0] = __builtin_amdgcn_mfma_f32_16x16x32_bf16(a0, b0, acc[0][0], 0, 0, 0);
                    acc[0][1] = __builtin_amdgcn_mfma_f32_16x16x32_bf16(a0, b1, acc[0][1], 0, 0, 0);
                    acc[1][0] = __builtin_amdgcn_mfma_f32_16x16x32_bf16(a1, b0, acc[1][0], 0, 0, 0);
                    acc[1][1] = __builtin_amdgcn_mfma_f32_16x16x32_bf16(a1, b1, acc[1][1], 0, 0, 0);
                }

                #pragma unroll
                for (int r = 0; r < 4; ++r) {
                    float a00 = acc[0][0][r], a01 = acc[0][1][r];
                    float a10 = acc[1][0][r], a11 = acc[1][1][r];
                    float e00 = __shfl_xor(a00, 8);
                    float e01 = __shfl_xor(a01, 8);
                    float e10 = __shfl_xor(a10, 8);
                    float e11 = __shfl_xor(a11, 8);
                    float gi, gf, gg, go;
                    if (mfS == 0) { gi = a00; gf = e00; gg = a01; go = e01; }
                    else          { gi = e10; gf = a10; gg = e11; go = a11; }
                    gi += b1v[0]; gf += b1v[1]; gg += b1v[2]; go += b1v[3];
                    int bb = row0 + mfS * 16 + kg * 4 + r;
                    float ii = sigm(gi), ff = sigm(gf), oo = sigm(go);
                    float tg = tanhf(gg);
                    size_t ci = ((size_t)cell * B + bb) * H + jj;
                    float cn = ff * cv[r] + ii * tg;
                    cst[ci] = cn;
                    float hn = oo * tanhf(cn);
                    stc2(&hb16[((size_t)(cell * 2 + parW) * B + bb) * H + jj], f2b(hn));
                }
            }
            if (p < NPH - 1) gbar(cnt, p);
        }
    } else {
        // ================= logits =================
        const int b = (bid - 192) * 8 + wave;
        const int c = lane & 31, kh = lane >> 5;
        const int half = lane >> 5, qq = lane & 31;
        const int sww = (c & 7) << 4;
        const int rowbase = c * 2048;
        const int lenb = lens[b];
        const float bo = (c < NC) ? bout[c] : 0.f;
        char* scr = smem + 57344 + wave * 2048;

        for (int p = 0; p < NPH; ++p) {
            if (p >= 2) {
                const int t2 = p - 2, parL = p & 1;
                // cooperative y2 stage: lane loads 32B, writes to wave scratch
                {
                    const ushort_t* src = hb16 + (size_t)((2 + half) * 2 + parL) * BH
                                        + (size_t)b * H + qq * 16;
                    bf16x8 v0 = ldc16(src);
                    bf16x8 v1 = ldc16(src + 8);
                    char* dst = scr + half * 1024 + qq * 32;
                    *(bf16x8*)dst = v0;
                    *(bf16x8*)(dst + 16) = v1;
                }
                __syncthreads();
                float sum = 0.f;
                if (c < NC) {
                    const char* ybase = scr + kh * 1024;
                    #pragma unroll 8
                    for (int t = 0; t < 64; ++t) {
                        bf16x8 v = *(const bf16x8*)(ybase + t * 16);
                        bf16x8 w = *(const bf16x8*)(smem + rowbase + ((kh * 1024 + t * 16) ^ sww));
                        #pragma unroll
                        for (int i = 0; i < 8; ++i) sum += (float)v[i] * (float)w[i];
                    }
                }
                sum += __shfl_xor(sum, 32);
                if (kh == 0 && c < NC) {
                    float val = sum + bo;
                    out[((size_t)b * T + t2) * NC + c] = (t2 < lenb) ? val : 0.f;
                }
            }
            if (p < NPH - 1) gbar(cnt, p);
        }
    }
}

// ---------------- launch ----------------

extern "C" void kernel_launch(void* const* d_in, const int* in_sizes, int n_in,
                              void* d_out, int out_size, void* d_ws, size_t ws_size,
                              hipStream_t stream) {
    const int*   tok   = (const int*)d_in[0];
    const int*   lens  = (const int*)d_in[1];
    const float* h0    = (const float*)d_in[2];
    const float* c0    = (const float*)d_in[3];
    const float* embed = (const float*)d_in[4];
    const float* Wih0  = (const float*)d_in[5];
    const float* Wih1  = (const float*)d_in[6];
    const float* Whh   = (const float*)d_in[7];
    const float* bih   = (const float*)d_in[8];
    const float* bhh   = (const float*)d_in[9];
    const float* Wout  = (const float*)d_in[10];
    const float* bout  = (const float*)d_in[11];
    float* out = (float*)d_out;

    ushort_t* hb16  = (ushort_t*)d_ws;                      // [4][2][B][H] bf16
    float*    fbase = (float*)(hb16 + (size_t)4 * 2 * B * H);
    float*    cst   = fbase;                                // [4][B][H] f32
    float*    G0    = cst + (size_t)4 * B * H;              // [2][28][2048] f32
    float*    bias1 = G0 + 2 * NE * FH;                     // [2][2048] f32
    int*      cnt   = (int*)(bias1 + 2 * FH);               // [NPH][NCELL]

    (void)hipFuncSetAttribute((const void*)k_persist,
                              hipFuncAttributeMaxDynamicSharedMemorySize, LDS_BYTES);

    k_init<<<(NPH * NCELL + 255) / 256, 256, 0, stream>>>(cnt);
    k_g0<<<(2 * NE * FH + 255) / 256, 256, 0, stream>>>(embed, Wih0, bih, bhh, G0, bias1);
    k_state<<<(4 * B * H + 255) / 256, 256, 0, stream>>>(h0, c0, cst, hb16);
    k_len<<<1, 256, 0, stream>>>(lens, out + (size_t)B * T * NC);

    k_persist<<<NBLK, 512, LDS_BYTES, stream>>>(Whh, Wih1, G0, bias1, cst, hb16,
                                                tok, lens, Wout, bout, out, cnt);
}

// Round 5
// 24421.901 us; speedup vs baseline: 1.5167x; 1.1734x over previous
//
#include <hip/hip_runtime.h>
#include <hip/hip_bf16.h>
#include <stdint.h>

typedef unsigned short ushort_t;
typedef unsigned long long u64_t;

#define H   512
#define E   128
#define NC  27
#define NE  28
#define B   256
#define T   512
#define FH  2048        // 4*H
#define NPH (T + 2)     // phases 0..T+1
#define NBLK 224        // 64 L0 + 128 L1 + 32 OUT
#define NCELL 16
#define LDS_BYTES (96 * 1024)

typedef __bf16 bf16x8 __attribute__((ext_vector_type(8)));
typedef float  f32x4  __attribute__((ext_vector_type(4)));

__device__ __forceinline__ ushort_t f2b(float x) {
    uint32_t u = __float_as_uint(x);
    uint32_t r = (u + 0x7FFFu + ((u >> 16) & 1u)) >> 16;
    return (ushort_t)r;
}
__device__ __forceinline__ float sigm(float x) {
    return 1.f / (1.f + __expf(-x));
}
__device__ __forceinline__ bf16x8 ldg8(const ushort_t* p) {
    return *(const bf16x8*)p;       // plain cached global_load_dwordx4
}
// write-through agent store (2B) — no dirty L2 line, visible at LLC
__device__ __forceinline__ void stc2(ushort_t* p, ushort_t v) {
    __hip_atomic_store(p, v, __ATOMIC_RELAXED, __HIP_MEMORY_SCOPE_AGENT);
}
__device__ __forceinline__ void stc4f(float* p, float v) {
    __hip_atomic_store(p, v, __ATOMIC_RELAXED, __HIP_MEMORY_SCOPE_AGENT);
}

// ---------------- setup kernels ----------------

__global__ void k_init(int* __restrict__ cnt) {
    int i = blockIdx.x * blockDim.x + threadIdx.x;
    if (i < NPH * NCELL) cnt[i] = 0;
}

// G0 layout: [cell][token][j][gate] f32  (gate quad contiguous -> one float4 gather)
__global__ void k_g0(const float* __restrict__ embed, const float* __restrict__ Wih0,
                     const float* __restrict__ bih, const float* __restrict__ bhh,
                     float* __restrict__ G0, float* __restrict__ bias1) {
    int i = blockIdx.x * blockDim.x + threadIdx.x;
    if (i < 2 * NE * FH) {
        int d = i / (NE * FH);
        int rem = i % (NE * FH);
        int e = rem / FH;
        int n = rem % FH;
        int g = n >> 9, j = n & 511;
        const float* er = embed + (size_t)e * E;
        const float* wr = Wih0 + ((size_t)d * FH + n) * E;
        float s = 0.f;
        #pragma unroll 8
        for (int k = 0; k < E; ++k) s += er[k] * wr[k];
        G0[(((size_t)d * NE + e) * 512 + j) * 4 + g]
            = s + bih[(size_t)d * FH + n] + bhh[(size_t)d * FH + n];
    }
    if (i < 2 * FH) bias1[i] = bih[2 * FH + i] + bhh[2 * FH + i];
}

__global__ void k_state(const float* __restrict__ h0, const float* __restrict__ c0,
                        float* __restrict__ cst, ushort_t* __restrict__ hb16) {
    int i = blockIdx.x * blockDim.x + threadIdx.x;
    if (i >= 4 * B * H) return;
    cst[i] = c0[i];
    int cell = i / (B * H);
    int rem  = i % (B * H);
    hb16[((size_t)(cell * 2 + 1)) * (B * H) + rem] = f2b(h0[i]);   // parity 1 = step -1
}

__global__ void k_tokT(const int* __restrict__ tok, int* __restrict__ tokT) {
    int i = blockIdx.x * blockDim.x + threadIdx.x;
    if (i < B * T) {
        int b = i / T, t = i % T;
        tokT[(size_t)t * B + b] = tok[i];
    }
}

__global__ void k_len(const int* __restrict__ lens, float* __restrict__ out_len) {
    int i = threadIdx.x;
    if (i < B) out_len[i] = (float)lens[i];
}

// ---------------- grid barrier ----------------
// Relaxed arrival + relaxed poll (no cache ops), then ONE acquire-agent fence
// (single buffer_inv) so the next phase's plain loads see fresh LLC data.
__device__ __forceinline__ void gbar(int* cnt, int p) {
    __syncthreads();
    if (threadIdx.x == 0) {
        int* base = cnt + p * NCELL;
        __hip_atomic_fetch_add(base + (blockIdx.x & (NCELL - 1)), 1,
                               __ATOMIC_RELAXED, __HIP_MEMORY_SCOPE_AGENT);
        int total;
        do {
            total = 0;
            #pragma unroll
            for (int c2 = 0; c2 < NCELL; ++c2)
                total += __hip_atomic_load(base + c2, __ATOMIC_RELAXED, __HIP_MEMORY_SCOPE_AGENT);
            if (total < NBLK) __builtin_amdgcn_s_sleep(2);
        } while (total < NBLK);
    }
    __syncthreads();
    __builtin_amdgcn_fence(__ATOMIC_ACQUIRE, "agent");
}

// Phase p: L0 step t=p (p<T); L1 step s=p-1 (1<=p<=T); OUT logits t2=p-2 (p>=2).
// hb16: [cell][parity][B][H] bf16, parity(step)=step&1.
__global__ __launch_bounds__(512, 2) void k_persist(
    const float* __restrict__ Whh, const float* __restrict__ Wih1,
    const float* __restrict__ G0, const float* __restrict__ bias1,
    const float* __restrict__ cst, ushort_t* __restrict__ hb16,
    const int* __restrict__ tokT, const int* __restrict__ lens,
    const float* __restrict__ Wout, const float* __restrict__ bout,
    float* __restrict__ out, int* __restrict__ cnt)
{
    extern __shared__ char smem[];
    const int bid = blockIdx.x;
    const int tid = threadIdx.x;
    const int lane = tid & 63, wave = tid >> 6;
    const int lrow = lane & 15, kg = lane >> 4;
    const int row0 = wave * 32;
    const int BH = B * H;
    const int sw16 = (lrow & 7) << 4;

    // ---- one-time: stage weights into LDS (f32 -> bf16, XOR-swizzled) ----
    if (bid < 64) {
        const int cell = bid >> 5, jt = bid & 31, j0 = jt * 16;
        const float* Wsrc = Whh + (size_t)cell * FH * H;
        for (int r = wave; r < 64; r += 8) {
            int grow = (r >> 4) * 512 + j0 + (r & 15);
            const float* src = Wsrc + (size_t)grow * H;
            int sw = (r & 7) << 4;
            for (int c = lane; c < H; c += 64) {
                int byte = ((r * H + c) * 2) ^ sw;
                *(ushort_t*)(smem + byte) = f2b(src[c]);
            }
        }
    } else if (bid < 192) {
        const int q = bid - 64, cell = 2 + (q >> 6), jt = q & 63, j0 = jt * 8;
        const float* Wi = Wih1 + (size_t)(cell - 2) * FH * (2 * H);
        const float* Wh = Whh + (size_t)cell * FH * H;
        for (int r = wave; r < 32; r += 8) {
            int grow = (r >> 3) * 512 + j0 + (r & 7);
            const float* si = Wi + (size_t)grow * (2 * H);
            const float* sh = Wh + (size_t)grow * H;
            int sw = (r & 7) << 4;
            for (int c = lane; c < 1536; c += 64) {
                float v = (c < 1024) ? si[c] : sh[c - 1024];
                int byte = ((r * 1536 + c) * 2) ^ sw;
                *(ushort_t*)(smem + byte) = f2b(v);
            }
        }
    } else {
        for (int r = wave; r < NC; r += 8) {
            const float* src = Wout + (size_t)r * (2 * H);
            int sw = (r & 7) << 4;
            for (int c = lane; c < 2 * H; c += 64) {
                int byte = ((r * (2 * H) + c) * 2) ^ sw;
                *(ushort_t*)(smem + byte) = f2b(src[c]);
            }
        }
    }
    __syncthreads();

    if (bid < 64) {
        // ================= layer 0 =================
        const int cell = bid >> 5, jt = bid & 31, j0 = jt * 16;
        const int j = j0 + lrow;
        const size_t ro = (size_t)(row0 + lrow) * H + kg * 8;

        // c-state lives in registers for the whole sequence
        float cv[8];
        #pragma unroll
        for (int i = 0; i < 8; ++i) {
            int bb = row0 + (i >> 2) * 16 + kg * 4 + (i & 3);
            cv[i] = cst[((size_t)cell * B + bb) * H + j];
        }

        for (int p = 0; p < NPH; ++p) {
            if (p < T) {
                const int parR = (p + 1) & 1, parW = p & 1;
                const ushort_t* ar0 = hb16 + (size_t)(cell * 2 + parR) * BH + ro;
                const ushort_t* ar1 = ar0 + (size_t)16 * H;

                bf16x8 rb0[8], rb1[8];
                #pragma unroll
                for (int q = 0; q < 8; ++q) {
                    rb0[q] = ldg8(ar0 + q * 32);
                    rb1[q] = ldg8(ar1 + q * 32);
                }

                int tkv[8];
                #pragma unroll
                for (int i = 0; i < 8; ++i) {
                    int bb = row0 + (i >> 2) * 16 + kg * 4 + (i & 3);
                    tkv[i] = tokT[(size_t)p * B + bb];
                }
                f32x4 g0v[8];
                #pragma unroll
                for (int i = 0; i < 8; ++i)
                    g0v[i] = *(const f32x4*)(G0 + (((size_t)cell * NE + tkv[i]) * 512 + j) * 4);

                f32x4 acc[2][4];
                #pragma unroll
                for (int m = 0; m < 2; ++m)
                    #pragma unroll
                    for (int g = 0; g < 4; ++g) acc[m][g] = (f32x4){0.f, 0.f, 0.f, 0.f};

                #pragma unroll
                for (int t = 0; t < 16; ++t) {
                    bf16x8 a0 = rb0[t & 7];
                    bf16x8 a1 = rb1[t & 7];
                    if (t + 8 < 16) {
                        rb0[t & 7] = ldg8(ar0 + (t + 8) * 32);
                        rb1[t & 7] = ldg8(ar1 + (t + 8) * 32);
                    }
                    int cb = (kg * 16 + t * 64) ^ sw16;
                    #pragma unroll
                    for (int g = 0; g < 4; ++g) {
                        bf16x8 bb = *(const bf16x8*)(smem + (g * 16 + lrow) * 1024 + cb);
                        acc[0][g] = __builtin_amdgcn_mfma_f32_16x16x32_bf16(a0, bb, acc[0][g], 0, 0, 0);
                        acc[1][g] = __builtin_amdgcn_mfma_f32_16x16x32_bf16(a1, bb, acc[1][g], 0, 0, 0);
                    }
                }

                #pragma unroll
                for (int i = 0; i < 8; ++i) {
                    int mf = i >> 2, r = i & 3;
                    int bb = row0 + mf * 16 + kg * 4 + r;
                    float gi = acc[mf][0][r] + g0v[i][0];
                    float gf = acc[mf][1][r] + g0v[i][1];
                    float gg = acc[mf][2][r] + g0v[i][2];
                    float go = acc[mf][3][r] + g0v[i][3];
                    float ii = sigm(gi), ff = sigm(gf), oo = sigm(go);
                    float tg = tanhf(gg);
                    float cn = ff * cv[i] + ii * tg;
                    cv[i] = cn;
                    float hn = oo * tanhf(cn);
                    stc2(&hb16[((size_t)(cell * 2 + parW) * B + bb) * H + j], f2b(hn));
                }
            }
            if (p < NPH - 1) gbar(cnt, p);
        }
    } else if (bid < 192) {
        // ================= layer 1 =================
        const int q = bid - 64, cell = 2 + (q >> 6), jt = q & 63, j0 = jt * 8;
        const int cc = lrow;
        const int jj = j0 + (cc & 7);
        const int mfS = cc >> 3;
        const size_t ro = (size_t)(row0 + lrow) * H + kg * 8;

        float b1v[4];
        #pragma unroll
        for (int g = 0; g < 4; ++g) b1v[g] = bias1[(size_t)(cell - 2) * FH + g * 512 + jj];

        float cv[4];
        #pragma unroll
        for (int r = 0; r < 4; ++r) {
            int bb = row0 + mfS * 16 + kg * 4 + r;
            cv[r] = cst[((size_t)cell * B + bb) * H + jj];
        }

        for (int p = 0; p < NPH; ++p) {
            if (p >= 1 && p <= T) {
                const int parY  = (p + 1) & 1;
                const int parR2 = p & 1;
                const int parW  = (p + 1) & 1;
                const ushort_t* base0 = hb16 + (size_t)(0 * 2 + parY) * BH + ro;
                const ushort_t* base1 = hb16 + (size_t)(1 * 2 + parY) * BH + ro;
                const ushort_t* base2 = hb16 + (size_t)(cell * 2 + parR2) * BH + ro;

                bf16x8 rb0[8], rb1[8];
                #pragma unroll
                for (int qq = 0; qq < 8; ++qq) {
                    rb0[qq] = ldg8(base0 + qq * 32);
                    rb1[qq] = ldg8(base0 + (size_t)16 * H + qq * 32);
                }

                f32x4 acc[2][2];
                #pragma unroll
                for (int m = 0; m < 2; ++m)
                    #pragma unroll
                    for (int n = 0; n < 2; ++n) acc[m][n] = (f32x4){0.f, 0.f, 0.f, 0.f};

                #pragma unroll
                for (int t = 0; t < 48; ++t) {
                    bf16x8 a0 = rb0[t & 7];
                    bf16x8 a1 = rb1[t & 7];
                    int tn = t + 8;
                    if (tn < 48) {
                        const ushort_t* bp = (tn < 16) ? base0 : (tn < 32) ? base1 : base2;
                        int off = (tn & 15) * 32;
                        rb0[t & 7] = ldg8(bp + off);
                        rb1[t & 7] = ldg8(bp + (size_t)16 * H + off);
                    }
                    int cb = (t * 64 + kg * 16) ^ sw16;
                    bf16x8 b0 = *(const bf16x8*)(smem + lrow * 3072 + cb);
                    bf16x8 b1 = *(const bf16x8*)(smem + (16 + lrow) * 3072 + cb);
                    acc[0][0] = __builtin_amdgcn_mfma_f32_16x16x32_bf16(a0, b0, acc[0][0], 0, 0, 0);
                    acc[0][1] = __builtin_amdgcn_mfma_f32_16x16x32_bf16(a0, b1, acc[0][1], 0, 0, 0);
                    acc[1][0] = __builtin_amdgcn_mfma_f32_16x16x32_bf16(a1, b0, acc[1][0], 0, 0, 0);
                    acc[1][1] = __builtin_amdgcn_mfma_f32_16x16x32_bf16(a1, b1, acc[1][1], 0, 0, 0);
                }

                #pragma unroll
                for (int r = 0; r < 4; ++r) {
                    float a00 = acc[0][0][r], a01 = acc[0][1][r];
                    float a10 = acc[1][0][r], a11 = acc[1][1][r];
                    float e00 = __shfl_xor(a00, 8);
                    float e01 = __shfl_xor(a01, 8);
                    float e10 = __shfl_xor(a10, 8);
                    float e11 = __shfl_xor(a11, 8);
                    float gi, gf, gg, go;
                    if (mfS == 0) { gi = a00; gf = e00; gg = a01; go = e01; }
                    else          { gi = e10; gf = a10; gg = e11; go = a11; }
                    gi += b1v[0]; gf += b1v[1]; gg += b1v[2]; go += b1v[3];
                    int bb = row0 + mfS * 16 + kg * 4 + r;
                    float ii = sigm(gi), ff = sigm(gf), oo = sigm(go);
                    float tg = tanhf(gg);
                    float cn = ff * cv[r] + ii * tg;
                    cv[r] = cn;
                    float hn = oo * tanhf(cn);
                    stc2(&hb16[((size_t)(cell * 2 + parW) * B + bb) * H + jj], f2b(hn));
                }
            }
            if (p < NPH - 1) gbar(cnt, p);
        }
    } else {
        // ================= logits =================
        const int b = (bid - 192) * 8 + wave;
        const int c = lane & 31, kh = lane >> 5;
        const int half = lane >> 5, qq = lane & 31;
        const int sww = (c & 7) << 4;
        const int rowbase = c * 2048;
        const int lenb = lens[b];
        const float bo = (c < NC) ? bout[c] : 0.f;
        char* scr = smem + 57344 + wave * 2048;

        for (int p = 0; p < NPH; ++p) {
            if (p >= 2) {
                const int t2 = p - 2, parL = p & 1;
                {
                    const ushort_t* src = hb16 + (size_t)((2 + half) * 2 + parL) * BH
                                        + (size_t)b * H + qq * 16;
                    bf16x8 v0 = ldg8(src);
                    bf16x8 v1 = ldg8(src + 8);
                    char* dst = scr + half * 1024 + qq * 32;
                    *(bf16x8*)dst = v0;
                    *(bf16x8*)(dst + 16) = v1;
                }
                __syncthreads();
                float sum = 0.f;
                if (c < NC) {
                    const char* ybase = scr + kh * 1024;
                    #pragma unroll 8
                    for (int t = 0; t < 64; ++t) {
                        bf16x8 v = *(const bf16x8*)(ybase + t * 16);
                        bf16x8 w = *(const bf16x8*)(smem + rowbase + ((kh * 1024 + t * 16) ^ sww));
                        #pragma unroll
                        for (int i = 0; i < 8; ++i) sum += (float)v[i] * (float)w[i];
                    }
                }
                sum += __shfl_xor(sum, 32);
                if (kh == 0 && c < NC) {
                    float val = (t2 < lenb) ? (sum + bo) : 0.f;
                    stc4f(&out[((size_t)b * T + t2) * NC + c], val);
                }
            }
            if (p < NPH - 1) gbar(cnt, p);
        }
    }
}

// ---------------- launch ----------------

extern "C" void kernel_launch(void* const* d_in, const int* in_sizes, int n_in,
                              void* d_out, int out_size, void* d_ws, size_t ws_size,
                              hipStream_t stream) {
    const int*   tok   = (const int*)d_in[0];
    const int*   lens  = (const int*)d_in[1];
    const float* h0    = (const float*)d_in[2];
    const float* c0    = (const float*)d_in[3];
    const float* embed = (const float*)d_in[4];
    const float* Wih0  = (const float*)d_in[5];
    const float* Wih1  = (const float*)d_in[6];
    const float* Whh   = (const float*)d_in[7];
    const float* bih   = (const float*)d_in[8];
    const float* bhh   = (const float*)d_in[9];
    const float* Wout  = (const float*)d_in[10];
    const float* bout  = (const float*)d_in[11];
    float* out = (float*)d_out;

    ushort_t* hb16  = (ushort_t*)d_ws;                      // [4][2][B][H] bf16
    float*    fbase = (float*)(hb16 + (size_t)4 * 2 * B * H);
    float*    cst   = fbase;                                // [4][B][H] f32 (init only)
    float*    G0    = cst + (size_t)4 * B * H;              // [2][28][512][4] f32
    float*    bias1 = G0 + 2 * NE * FH;                     // [2][2048] f32
    int*      cnt   = (int*)(bias1 + 2 * FH);               // [NPH][NCELL]
    int*      tokT  = cnt + NPH * NCELL;                    // [T][B]

    (void)hipFuncSetAttribute((const void*)k_persist,
                              hipFuncAttributeMaxDynamicSharedMemorySize, LDS_BYTES);

    k_init<<<(NPH * NCELL + 255) / 256, 256, 0, stream>>>(cnt);
    k_g0<<<(2 * NE * FH + 255) / 256, 256, 0, stream>>>(embed, Wih0, bih, bhh, G0, bias1);
    k_state<<<(4 * B * H + 255) / 256, 256, 0, stream>>>(h0, c0, cst, hb16);
    k_tokT<<<(B * T + 255) / 256, 256, 0, stream>>>(tok, tokT);
    k_len<<<1, 256, 0, stream>>>(lens, out + (size_t)B * T * NC);

    k_persist<<<NBLK, 512, LDS_BYTES, stream>>>(Whh, Wih1, G0, bias1, cst, hb16,
                                                tokT, lens, Wout, bout, out, cnt);
}